// Round 5
// baseline (126.866 us; speedup 1.0000x reference)
//
#include <hip/hip_runtime.h>

// Problem constants (fixed by setup_inputs)
constexpr int N_    = 4;
constexpr int C_    = 151;
constexpr int HW_   = 512 * 512;          // 262144
constexpr int NPIX_ = N_ * HW_;           // 1048576
constexpr int PX_   = 2;                  // pixels per thread
constexpr int NBLK_ = NPIX_ / (256 * PX_);// 2048 blocks = 8 blocks/CU
constexpr int OLD_CL_ = 100;
constexpr int IGNORE_ = 255;

__global__ __launch_bounds__(256, 8)   // 8 waves/EU -> cap VGPR at 64 -> 32 waves/CU
void wce_main(const float* __restrict__ inputs,
              const int*   __restrict__ targets,
              const float* __restrict__ probs,
              double*      __restrict__ acc) {
    const int q    = blockIdx.x * 256 + threadIdx.x;   // pair-pixel index
    const int pix0 = q * PX_;
    const int n    = pix0 / HW_;
    const int hw   = pix0 - n * HW_;
    const float* inp = inputs + (size_t)n * C_ * HW_ + hw;

    // targets for the 2 pixels
    const int2 t2 = *reinterpret_cast<const int2*>(targets + pix0);
    int t[PX_] = {t2.x, t2.y};
    int lab2c[PX_];
#pragma unroll
    for (int j = 0; j < PX_; ++j) {
        int l = (t[j] < OLD_CL_) ? 0 : t[j];       // lab2 (255 stays 255)
        lab2c[j] = (l > C_ - 1) ? (C_ - 1) : l;    // clip to C-1
        // lab2c is always 0 or in [100,150] — never in [1,100).
    }

    // seen/not-seen probs: [N,2,H,W]
    const float* pp = probs + (size_t)n * 2 * HW_ + hw;
    const float2 pa = *reinterpret_cast<const float2*>(pp);
    const float2 pb = *reinterpret_cast<const float2*>(pp + HW_);
    const float pav[PX_] = {pa.x, pa.y};
    const float pbv[PX_] = {pb.x, pb.y};

    float s[PX_], s100[PX_], e0[PX_], x0v[PX_], g[PX_];

    // --- channel 0 (peeled) ---
    {
        float2 x2 = *reinterpret_cast<const float2*>(inp);
        float xs[PX_] = {x2.x, x2.y};
#pragma unroll
        for (int j = 0; j < PX_; ++j) {
            x0v[j] = xs[j];
            e0[j]  = __expf(xs[j]);
            s[j]   = e0[j];
            g[j]   = xs[j];
        }
    }
    // --- channels 1..99: gather predicate provably false (lab2c ∉ [1,100)) ---
#pragma unroll 4
    for (int c = 1; c < OLD_CL_; ++c) {
        float2 x2 = *reinterpret_cast<const float2*>(inp + (size_t)c * HW_);
        float xs[PX_] = {x2.x, x2.y};
#pragma unroll
        for (int j = 0; j < PX_; ++j)
            s[j] += __expf(xs[j]);
    }
#pragma unroll
    for (int j = 0; j < PX_; ++j) s100[j] = s[j];  // sum(exp) over [0,100)
    // --- channels 100..150: gather lives only here ---
#pragma unroll 4
    for (int c = OLD_CL_; c < C_; ++c) {
        float2 x2 = *reinterpret_cast<const float2*>(inp + (size_t)c * HW_);
        float xs[PX_] = {x2.x, x2.y};
#pragma unroll
        for (int j = 0; j < PX_; ++j) {
            s[j] += __expf(xs[j]);
            g[j] = (c == lab2c[j]) ? xs[j] : g[j];
        }
    }

    float local = 0.f;
#pragma unroll
    for (int j = 0; j < PX_; ++j) {
        const float den    = __logf(s[j]);
        const float out_bg = x0v[j] - den;
        const float out_fg = __logf(s[j] - e0[j]) - den;
        const float out0n  = __logf(s100[j]) - den;

        const bool valid = (t[j] != IGNORE_);
        const int  mt    = valid ? t[j] : 0;

        float msn = fmaxf(pav[j], pbv[j]);
        msn = (msn > 0.5f) ? 1.0f : msn;
        const float w     = (mt == 0) ? msn : 0.f;
        const float f1    = 1.f - w;
        const float focal = f1 * f1;
        const float picked = (mt == 0) ? out_bg : out_fg;
        const float l1 = valid ? (-focal * picked) : 0.f;

        const int  lab2   = (t[j] < OLD_CL_) ? 0 : t[j];
        const bool valid2 = (lab2 != IGNORE_);
        const float val = (lab2c[j] == 0) ? out0n : (g[j] - den);
        const float l2  = valid2 ? (-val) : 0.f;

        local += l1 + l2;
    }

    // block reduction: wave64 shuffle -> LDS -> one double atomic per block
    // (no __threadfence — device fences per block were the R2/R3 regression)
    double d = (double)local;
#pragma unroll
    for (int off = 32; off >= 1; off >>= 1)
        d += __shfl_down(d, off, 64);

    __shared__ double lds[4];
    const int lane = threadIdx.x & 63;
    const int wid  = threadIdx.x >> 6;
    if (lane == 0) lds[wid] = d;
    __syncthreads();
    if (threadIdx.x == 0) {
        const double bsum = lds[0] + lds[1] + lds[2] + lds[3];
        atomicAdd(acc, bsum);
    }
}

__global__ void wce_final(const double* __restrict__ acc, float* __restrict__ out) {
    out[0] = (float)(acc[0] / (double)NPIX_);
}

extern "C" void kernel_launch(void* const* d_in, const int* in_sizes, int n_in,
                              void* d_out, int out_size, void* d_ws, size_t ws_size,
                              hipStream_t stream) {
    const float* inputs  = (const float*)d_in[0];
    const int*   targets = (const int*)  d_in[1];
    const float* probs   = (const float*)d_in[2];
    // d_in[3] = task_num (unused by the math)
    float*  out = (float*) d_out;
    double* acc = (double*)d_ws;

    // ws is not re-poisoned between timed replays — zero it each call.
    hipMemsetAsync(acc, 0, sizeof(double), stream);
    wce_main<<<NBLK_, 256, 0, stream>>>(inputs, targets, probs, acc);
    wce_final<<<1, 1, 0, stream>>>(acc, out);
}

// Round 6
// 117.985 us; speedup vs baseline: 1.0753x; 1.0753x over previous
//
#include <hip/hip_runtime.h>

// Problem constants (fixed by setup_inputs)
constexpr int N_    = 4;
constexpr int C_    = 151;
constexpr int HW_   = 512 * 512;          // 262144
constexpr int NPIX_ = N_ * HW_;           // 1048576
constexpr int QUADS_ = NPIX_ / 4;         // 262144
constexpr int NBLK_  = QUADS_ / 256;      // 1024 blocks = 4/CU, 16 waves/CU
constexpr int OLD_CL_ = 100;
constexpr int IGNORE_ = 255;

__global__ __launch_bounds__(256)
void wce_main(const float* __restrict__ inputs,
              const int*   __restrict__ targets,
              const float* __restrict__ probs,
              float*       __restrict__ out) {
    const int q    = blockIdx.x * 256 + threadIdx.x;   // quad-pixel index
    const int pix0 = q * 4;
    const int n    = pix0 / HW_;
    const int hw   = pix0 - n * HW_;
    const float* inp = inputs + (size_t)n * C_ * HW_ + hw;

    // targets for the 4 pixels
    const int4 t4 = *reinterpret_cast<const int4*>(targets + pix0);
    int t[4] = {t4.x, t4.y, t4.z, t4.w};
    int lab2c[4];
#pragma unroll
    for (int j = 0; j < 4; ++j) {
        int l = (t[j] < OLD_CL_) ? 0 : t[j];       // lab2 (255 stays 255)
        lab2c[j] = (l > C_ - 1) ? (C_ - 1) : l;    // clip to C-1
        // lab2c is always 0 or in [100,150] — never in [1,100).
    }

    // seen/not-seen probs: [N,2,H,W]
    const float* pp = probs + (size_t)n * 2 * HW_ + hw;
    const float4 pa = *reinterpret_cast<const float4*>(pp);
    const float4 pb = *reinterpret_cast<const float4*>(pp + HW_);
    const float pav[4] = {pa.x, pa.y, pa.z, pa.w};
    const float pbv[4] = {pb.x, pb.y, pb.z, pb.w};

    float s[4], s100[4], e0[4], x0v[4], g[4];

    // --- channel 0 (peeled) ---
    {
        float4 x4 = *reinterpret_cast<const float4*>(inp);
        float xs[4] = {x4.x, x4.y, x4.z, x4.w};
#pragma unroll
        for (int j = 0; j < 4; ++j) {
            x0v[j] = xs[j];
            e0[j]  = __expf(xs[j]);
            s[j]   = e0[j];
            g[j]   = xs[j];
        }
    }
    // --- channels 1..99: gather predicate provably false (lab2c ∉ [1,100)) ---
#pragma unroll 4
    for (int c = 1; c < OLD_CL_; ++c) {
        float4 x4 = *reinterpret_cast<const float4*>(inp + (size_t)c * HW_);
        float xs[4] = {x4.x, x4.y, x4.z, x4.w};
#pragma unroll
        for (int j = 0; j < 4; ++j)
            s[j] += __expf(xs[j]);
    }
#pragma unroll
    for (int j = 0; j < 4; ++j) s100[j] = s[j];  // sum(exp) over [0,100)
    // --- channels 100..150: gather lives only here ---
#pragma unroll 4
    for (int c = OLD_CL_; c < C_; ++c) {
        float4 x4 = *reinterpret_cast<const float4*>(inp + (size_t)c * HW_);
        float xs[4] = {x4.x, x4.y, x4.z, x4.w};
#pragma unroll
        for (int j = 0; j < 4; ++j) {
            s[j] += __expf(xs[j]);
            g[j] = (c == lab2c[j]) ? xs[j] : g[j];
        }
    }

    float local = 0.f;
#pragma unroll
    for (int j = 0; j < 4; ++j) {
        const float den    = __logf(s[j]);
        const float out_bg = x0v[j] - den;
        const float out_fg = __logf(s[j] - e0[j]) - den;
        const float out0n  = __logf(s100[j]) - den;

        const bool valid = (t[j] != IGNORE_);
        const int  mt    = valid ? t[j] : 0;

        float msn = fmaxf(pav[j], pbv[j]);
        msn = (msn > 0.5f) ? 1.0f : msn;
        const float w     = (mt == 0) ? msn : 0.f;
        const float f1    = 1.f - w;
        const float focal = f1 * f1;
        const float picked = (mt == 0) ? out_bg : out_fg;
        const float l1 = valid ? (-focal * picked) : 0.f;

        const int  lab2   = (t[j] < OLD_CL_) ? 0 : t[j];
        const bool valid2 = (lab2 != IGNORE_);
        const float val = (lab2c[j] == 0) ? out0n : (g[j] - den);
        const float l2  = valid2 ? (-val) : 0.f;

        local += l1 + l2;
    }

    // block reduction: wave64 shuffle -> LDS -> one scaled float atomic
    // directly into out (graph = memset + main, no final kernel).
    // No __threadfence — per-block device fences were the R2/R3 regression.
    double d = (double)local;
#pragma unroll
    for (int off = 32; off >= 1; off >>= 1)
        d += __shfl_down(d, off, 64);

    __shared__ double lds[4];
    const int lane = threadIdx.x & 63;
    const int wid  = threadIdx.x >> 6;
    if (lane == 0) lds[wid] = d;
    __syncthreads();
    if (threadIdx.x == 0) {
        const double bsum = lds[0] + lds[1] + lds[2] + lds[3];
        atomicAdd(out, (float)(bsum / (double)NPIX_));
    }
}

extern "C" void kernel_launch(void* const* d_in, const int* in_sizes, int n_in,
                              void* d_out, int out_size, void* d_ws, size_t ws_size,
                              hipStream_t stream) {
    const float* inputs  = (const float*)d_in[0];
    const int*   targets = (const int*)  d_in[1];
    const float* probs   = (const float*)d_in[2];
    // d_in[3] = task_num (unused by the math)
    float* out = (float*)d_out;

    // out is poisoned (not zeroed) before timing and not re-poisoned between
    // replays — zero it each call, then accumulate the mean into it.
    hipMemsetAsync(out, 0, sizeof(float), stream);
    wce_main<<<NBLK_, 256, 0, stream>>>(inputs, targets, probs, out);
}

// Round 7
// 116.801 us; speedup vs baseline: 1.0862x; 1.0101x over previous
//
#include <hip/hip_runtime.h>

// Problem constants (fixed by setup_inputs)
constexpr int N_    = 4;
constexpr int C_    = 151;
constexpr int HW_   = 512 * 512;          // 262144
constexpr int NPIX_ = N_ * HW_;           // 1048576
constexpr int BLK_  = 512;                // threads/block
constexpr int PX_   = 4;                  // pixels per thread
constexpr int NBLK_ = NPIX_ / (BLK_ * PX_); // 512 blocks = 2/CU, 16 waves/CU
constexpr int OLD_CL_ = 100;
constexpr int IGNORE_ = 255;

__global__ __launch_bounds__(BLK_)
void wce_main(const float* __restrict__ inputs,
              const int*   __restrict__ targets,
              const float* __restrict__ probs,
              float*       __restrict__ out) {
    const int q    = blockIdx.x * BLK_ + threadIdx.x;  // quad-pixel index
    const int pix0 = q * PX_;
    const int n    = pix0 / HW_;
    const int hw   = pix0 - n * HW_;
    const float* inp = inputs + (size_t)n * C_ * HW_ + hw;

    // targets for the 4 pixels
    const int4 t4 = *reinterpret_cast<const int4*>(targets + pix0);
    int t[4] = {t4.x, t4.y, t4.z, t4.w};
    int lab2c[4];
#pragma unroll
    for (int j = 0; j < 4; ++j) {
        int l = (t[j] < OLD_CL_) ? 0 : t[j];       // lab2 (255 stays 255)
        lab2c[j] = (l > C_ - 1) ? (C_ - 1) : l;    // clip to C-1
        // lab2c is always 0 or in [100,150] — never in [1,100).
    }

    // seen/not-seen probs: [N,2,H,W]
    const float* pp = probs + (size_t)n * 2 * HW_ + hw;
    const float4 pa = *reinterpret_cast<const float4*>(pp);
    const float4 pb = *reinterpret_cast<const float4*>(pp + HW_);
    const float pav[4] = {pa.x, pa.y, pa.z, pa.w};
    const float pbv[4] = {pb.x, pb.y, pb.z, pb.w};

    float s[4], s100[4], e0[4], x0v[4], g[4];

    // --- channel 0 (peeled) ---
    {
        float4 x4 = *reinterpret_cast<const float4*>(inp);
        float xs[4] = {x4.x, x4.y, x4.z, x4.w};
#pragma unroll
        for (int j = 0; j < 4; ++j) {
            x0v[j] = xs[j];
            e0[j]  = __expf(xs[j]);
            s[j]   = e0[j];
            g[j]   = xs[j];
        }
    }
    // --- channels 1..99: gather predicate provably false (lab2c ∉ [1,100)) ---
#pragma unroll 4
    for (int c = 1; c < OLD_CL_; ++c) {
        float4 x4 = *reinterpret_cast<const float4*>(inp + (size_t)c * HW_);
        float xs[4] = {x4.x, x4.y, x4.z, x4.w};
#pragma unroll
        for (int j = 0; j < 4; ++j)
            s[j] += __expf(xs[j]);
    }
#pragma unroll
    for (int j = 0; j < 4; ++j) s100[j] = s[j];  // sum(exp) over [0,100)
    // --- channels 100..150: gather lives only here ---
#pragma unroll 4
    for (int c = OLD_CL_; c < C_; ++c) {
        float4 x4 = *reinterpret_cast<const float4*>(inp + (size_t)c * HW_);
        float xs[4] = {x4.x, x4.y, x4.z, x4.w};
#pragma unroll
        for (int j = 0; j < 4; ++j) {
            s[j] += __expf(xs[j]);
            g[j] = (c == lab2c[j]) ? xs[j] : g[j];
        }
    }

    float local = 0.f;
#pragma unroll
    for (int j = 0; j < 4; ++j) {
        const float den    = __logf(s[j]);
        const float out_bg = x0v[j] - den;
        const float out_fg = __logf(s[j] - e0[j]) - den;
        const float out0n  = __logf(s100[j]) - den;

        const bool valid = (t[j] != IGNORE_);
        const int  mt    = valid ? t[j] : 0;

        float msn = fmaxf(pav[j], pbv[j]);
        msn = (msn > 0.5f) ? 1.0f : msn;
        const float w     = (mt == 0) ? msn : 0.f;
        const float f1    = 1.f - w;
        const float focal = f1 * f1;
        const float picked = (mt == 0) ? out_bg : out_fg;
        const float l1 = valid ? (-focal * picked) : 0.f;

        const int  lab2   = (t[j] < OLD_CL_) ? 0 : t[j];
        const bool valid2 = (lab2 != IGNORE_);
        const float val = (lab2c[j] == 0) ? out0n : (g[j] - den);
        const float l2  = valid2 ? (-val) : 0.f;

        local += l1 + l2;
    }

    // block reduction: wave64 shuffle -> LDS -> one scaled float atomic
    // directly into out. No __threadfence (R2/R3 lesson).
    double d = (double)local;
#pragma unroll
    for (int off = 32; off >= 1; off >>= 1)
        d += __shfl_down(d, off, 64);

    __shared__ double lds[BLK_ / 64];
    const int lane = threadIdx.x & 63;
    const int wid  = threadIdx.x >> 6;
    if (lane == 0) lds[wid] = d;
    __syncthreads();
    if (threadIdx.x == 0) {
        double bsum = 0.0;
#pragma unroll
        for (int i = 0; i < BLK_ / 64; ++i) bsum += lds[i];
        atomicAdd(out, (float)(bsum / (double)NPIX_));
    }
}

extern "C" void kernel_launch(void* const* d_in, const int* in_sizes, int n_in,
                              void* d_out, int out_size, void* d_ws, size_t ws_size,
                              hipStream_t stream) {
    const float* inputs  = (const float*)d_in[0];
    const int*   targets = (const int*)  d_in[1];
    const float* probs   = (const float*)d_in[2];
    // d_in[3] = task_num (unused by the math)
    float* out = (float*)d_out;

    // out is poisoned (not zeroed) before timing and not re-poisoned between
    // replays — zero it each call, then accumulate the mean into it.
    hipMemsetAsync(out, 0, sizeof(float), stream);
    wce_main<<<NBLK_, BLK_, 0, stream>>>(inputs, targets, probs, out);
}